// Round 5
// baseline (248.823 us; speedup 1.0000x reference)
//
#include <hip/hip_runtime.h>
#include <float.h>

#define K_NN 10
#define BATCH 8
#define CIN 6
#define NPTS 4096
#define COUT 64
#define NSEG 16
#define SEGLEN (NPTS / NSEG)    // 256
#define CHUNK 16
#define NCHUNK (SEGLEN / CHUNK) // 16
#define NWORD (SEGLEN / 32)     // 8
#define NEG_SLOPE 0.2f
#define BN_EPS 1e-5f

// ---- workspace layout (bytes) ----
// part[] (u16, 16 segs) aliases q[]: consumed by merge_kernel before feat writes q.
// u16 keeps SZ_Q identical to the verified 8-seg/int layout: 16*8*10*4096*2 = 10.49 MB.
static constexpr size_t OFF_IDX = 0;                                                   // int[8*10*4096]  (plane layout [b][j][n])
static constexpr size_t OFF_PTS = OFF_IDX + (size_t)BATCH * K_NN * NPTS * sizeof(int); // float4[8*4096]
static constexpr size_t OFF_Q   = OFF_PTS + (size_t)BATCH * NPTS * sizeof(float4);     // alias: q / part
static constexpr size_t SZ_Q    = (size_t)NSEG * BATCH * NPTS * K_NN * sizeof(unsigned short); // 10.49 MB
static constexpr size_t OFF_ST  = OFF_Q + SZ_Q;                                        // double[27]

__device__ __forceinline__ float wave_sum(float v) {
#pragma unroll
    for (int m = 32; m >= 1; m >>= 1) v += __shfl_xor(v, m, 64);
    return v;
}
__device__ __forceinline__ float wave_max(float v) {
#pragma unroll
    for (int m = 32; m >= 1; m >>= 1) v = fmaxf(v, __shfl_xor(v, m, 64));
    return v;
}

// pts stores (2x, 2y, 2z, ||p||^2); query coords pre-halved once per thread.
// d' = 2*inner - ||c||^2 -> 3 FMAs. Monotone shift of true distance, used
// consistently in knn_part/drain/merge. DO NOT reorder (bit-stable).
__device__ __forceinline__ float distp(float qx, float qy, float qz, float4 c) {
    return fmaf(c.x, qx, fmaf(c.y, qy, fmaf(c.z, qz, -c.w)));
}

__device__ __forceinline__ float fmax3(float a, float b, float c) {
    return fmaxf(fmaxf(a, b), c);   // fuses to v_max3_f32 (exact for non-NaN)
}

// 10-deep chunk-max chain level: { hi = max(cj,t); t = min(cj,t); cj = hi; }
#define CHL(cj) { float _hi = fmaxf(cj, t); t = fminf(cj, t); cj = _hi; }

// one conditional swap level of the insertion sort
#define CSWP(va, vb, ia, ib) \
    if (va > vb) { float _tv = va; va = vb; vb = _tv; int _ti = ia; ia = ib; ib = _ti; }

// exact strict-> insertion of (d,m) into descending list v0..v9 / i0..i9
#define INSERT10(dd, mm) \
    if ((dd) > v9) { \
        v9 = (dd); i9 = (mm); \
        CSWP(v9, v8, i9, i8) \
        CSWP(v8, v7, i8, i7) \
        CSWP(v7, v6, i7, i6) \
        CSWP(v6, v5, i6, i5) \
        CSWP(v5, v4, i5, i4) \
        CSWP(v4, v3, i4, i3) \
        CSWP(v3, v2, i3, i2) \
        CSWP(v2, v1, i2, i1) \
        CSWP(v1, v0, i1, i0) \
    }

// ---- Kernel P: pack (2x,2y,2z,||p||^2) per point; block 0 zeroes stats ----
__global__ __launch_bounds__(256) void prep_pts(const float* __restrict__ x,
                                                float4* __restrict__ pts,
                                                double* __restrict__ stats) {
    if (blockIdx.x == 0 && threadIdx.x < 27) stats[threadIdx.x] = 0.0;
    int t = blockIdx.x * 256 + threadIdx.x;   // 0..32767
    int b = t >> 12;
    int n = t & (NPTS - 1);
    const float* xb = x + (size_t)b * CIN * NPTS;
    float x0 = xb[n];
    float x1 = xb[NPTS + n];
    float x2 = xb[2 * NPTS + n];
    pts[t] = make_float4(2.0f * x0, 2.0f * x1, 2.0f * x2, x0 * x0 + x1 * x1 + x2 * x2);
}

// ---- Kernel A1: per-segment exact top-10 (lean single-wave, 16 segments) ----
// ROUND-5: NSEG 8->16 doubles wave count 4096->8192 (8/SIMD) to hide the
// s_load/gather latency (real VALUBusy ~43%: derived counter uses gfx94x
// 4-cyc/inst formula, ~2x inflated on SIMD-32 CDNA4).
// thr = 10th largest of 16 chunk maxima: still >=10 distinct chunks with an
// element >= thr => thr <= exact v10. Survivor bitmask exact, no overflow.
__global__ __launch_bounds__(256, 6) void knn_part(const float4* __restrict__ pts,
                                                   unsigned short* __restrict__ part) {
    int b = blockIdx.y;
    int s = blockIdx.z;
    int n = blockIdx.x * 256 + threadIdx.x;
    const float4* p = pts + (size_t)b * NPTS;   // wave-uniform base -> scalar loads
    float4 q4 = p[n];
    float qx = 0.5f * q4.x, qy = 0.5f * q4.y, qz = 0.5f * q4.z;
    int m0 = s * SEGLEN;

    // ---- phase 1: threshold from chunk maxima ----
    float c0 = -FLT_MAX, c1 = -FLT_MAX, c2 = -FLT_MAX, c3 = -FLT_MAX, c4 = -FLT_MAX;
    float c5 = -FLT_MAX, c6 = -FLT_MAX, c7 = -FLT_MAX, c8 = -FLT_MAX, c9 = -FLT_MAX;

    for (int ch = 0; ch < NCHUNK; ch++) {
        const float4* cp = p + (m0 + ch * CHUNK);
        float d0  = distp(qx, qy, qz, cp[0]);
        float d1  = distp(qx, qy, qz, cp[1]);
        float d2  = distp(qx, qy, qz, cp[2]);
        float d3  = distp(qx, qy, qz, cp[3]);
        float d4  = distp(qx, qy, qz, cp[4]);
        float d5  = distp(qx, qy, qz, cp[5]);
        float d6  = distp(qx, qy, qz, cp[6]);
        float d7  = distp(qx, qy, qz, cp[7]);
        float d8  = distp(qx, qy, qz, cp[8]);
        float d9  = distp(qx, qy, qz, cp[9]);
        float d10 = distp(qx, qy, qz, cp[10]);
        float d11 = distp(qx, qy, qz, cp[11]);
        float d12 = distp(qx, qy, qz, cp[12]);
        float d13 = distp(qx, qy, qz, cp[13]);
        float d14 = distp(qx, qy, qz, cp[14]);
        float d15 = distp(qx, qy, qz, cp[15]);
        float a0 = fmax3(d0, d1, d2);
        float a1 = fmax3(d3, d4, d5);
        float a2 = fmax3(d6, d7, d8);
        float a3 = fmax3(d9, d10, d11);
        float a4 = fmax3(d12, d13, d14);
        float t = fmaxf(fmax3(fmax3(a0, a1, a2), a3, a4), d15);
        CHL(c0) CHL(c1) CHL(c2) CHL(c3) CHL(c4)
        CHL(c5) CHL(c6) CHL(c7) CHL(c8) CHL(c9)
    }
    float thr = c9;   // 10th-largest chunk max (<= exact v10)

    // ---- phase 2 + drain: bitmask survivors, exact strict-> insert ----
    float v0 = -FLT_MAX, v1 = -FLT_MAX, v2 = -FLT_MAX, v3 = -FLT_MAX, v4 = -FLT_MAX;
    float v5 = -FLT_MAX, v6 = -FLT_MAX, v7 = -FLT_MAX, v8 = -FLT_MAX, v9 = -FLT_MAX;
    int i0 = 0, i1 = 0, i2 = 0, i3 = 0, i4 = 0;
    int i5 = 0, i6 = 0, i7 = 0, i8 = 0, i9 = 0;

    for (int w = 0; w < NWORD; w++) {
        const float4* cp = p + (m0 + w * 32);
        unsigned int mask = 0u;
#pragma unroll
        for (int u = 0; u < 32; u++) {
            float d = distp(qx, qy, qz, cp[u]);
            mask = (mask << 1) | (d >= thr ? 1u : 0u);   // point u -> bit (31-u)
        }
        int base = m0 + w * 32;
        while (mask) {
            int j = __builtin_clz(mask);        // MSB-first == ascending m
            mask ^= (0x80000000u >> j);
            int m = base + j;
            float4 cc = p[m];                   // divergent, L1-hot (segment = 4 KB)
            float d = distp(qx, qy, qz, cc);
            INSERT10(d, m)
        }
    }

    unsigned short* o = part + (((size_t)s * BATCH + b) * K_NN) * NPTS + n;
    o[(size_t)0 * NPTS] = (unsigned short)i0;
    o[(size_t)1 * NPTS] = (unsigned short)i1;
    o[(size_t)2 * NPTS] = (unsigned short)i2;
    o[(size_t)3 * NPTS] = (unsigned short)i3;
    o[(size_t)4 * NPTS] = (unsigned short)i4;
    o[(size_t)5 * NPTS] = (unsigned short)i5;
    o[(size_t)6 * NPTS] = (unsigned short)i6;
    o[(size_t)7 * NPTS] = (unsigned short)i7;
    o[(size_t)8 * NPTS] = (unsigned short)i8;
    o[(size_t)9 * NPTS] = (unsigned short)i9;
}

// ---- Kernel A2: merge 16 segment lists -> global top-10 (re-evals 160 cands) ----
__global__ __launch_bounds__(256, 4) void merge_kernel(const float4* __restrict__ pts,
                                                       const unsigned short* __restrict__ part,
                                                       int* __restrict__ idxo) {
    int b = blockIdx.y;
    int n = blockIdx.x * 256 + threadIdx.x;
    const float4* p = pts + (size_t)b * NPTS;
    float4 q4 = p[n];
    float qx = 0.5f * q4.x, qy = 0.5f * q4.y, qz = 0.5f * q4.z;

    float v0 = -FLT_MAX, v1 = -FLT_MAX, v2 = -FLT_MAX, v3 = -FLT_MAX, v4 = -FLT_MAX;
    float v5 = -FLT_MAX, v6 = -FLT_MAX, v7 = -FLT_MAX, v8 = -FLT_MAX, v9 = -FLT_MAX;
    int i0 = 0, i1 = 0, i2 = 0, i3 = 0, i4 = 0;
    int i5 = 0, i6 = 0, i7 = 0, i8 = 0, i9 = 0;

#pragma unroll 4
    for (int s = 0; s < NSEG; s++) {
        const unsigned short* pp = part + (((size_t)s * BATCH + b) * K_NN) * NPTS + n;
#pragma unroll
        for (int j = 0; j < K_NN; j++) {
            int m = pp[(size_t)j * NPTS];
            float4 cc = p[m];                    // divergent but L1/L2-resident
            float d = distp(qx, qy, qz, cc);
            INSERT10(d, m)
        }
    }

    // plane layout [b][j][n] : coalesced write, coalesced read in feat
    int* o = idxo + (size_t)b * K_NN * NPTS + n;
    o[(size_t)0 * NPTS] = i0;
    o[(size_t)1 * NPTS] = i1;
    o[(size_t)2 * NPTS] = i2;
    o[(size_t)3 * NPTS] = i3;
    o[(size_t)4 * NPTS] = i4;
    o[(size_t)5 * NPTS] = i5;
    o[(size_t)6 * NPTS] = i6;
    o[(size_t)7 * NPTS] = i7;
    o[(size_t)8 * NPTS] = i8;
    o[(size_t)9 * NPTS] = i9;
}

// ---- Kernel B: gather + center + q[b,o,n] = max_k (W feat) + moment stats ----
__global__ __launch_bounds__(256) void feat_kernel(const float4* __restrict__ pts,
                                                   const float* __restrict__ x,
                                                   const float* __restrict__ W,
                                                   const int* __restrict__ idx,
                                                   float* __restrict__ q,
                                                   double* __restrict__ stats) {
    __shared__ float sW[COUT * CIN];
    __shared__ float sred[4][27];
    for (int i = threadIdx.x; i < COUT * CIN; i += 256) sW[i] = W[i];
    __syncthreads();

    int b = blockIdx.y;
    int n = blockIdx.x * 256 + threadIdx.x;
    const float* xb = x + (size_t)b * CIN * NPTS;
    const float4* p = pts + (size_t)b * NPTS;

    int nb[K_NN];
#pragma unroll
    for (int k = 0; k < K_NN; k++) nb[k] = idx[((size_t)b * K_NN + k) * NPTS + n];

    float f[CIN][K_NN];
#pragma unroll
    for (int k = 0; k < K_NN; k++) {
        float4 c = p[nb[k]];                    // xyz in one 16B gather (doubled)
        f[0][k] = 0.5f * c.x; f[1][k] = 0.5f * c.y; f[2][k] = 0.5f * c.z;
    }
#pragma unroll
    for (int c = 3; c < CIN; c++)
#pragma unroll
        for (int k = 0; k < K_NN; k++)
            f[c][k] = xb[c * NPTS + nb[k]];

    // center xyz over k, scale by 10
#pragma unroll
    for (int c = 0; c < 3; c++) {
        float s = 0.f;
#pragma unroll
        for (int k = 0; k < K_NN; k++) s += f[c][k];
        float m = s / 10.0f;
#pragma unroll
        for (int k = 0; k < K_NN; k++) f[c][k] = (f[c][k] - m) * 10.0f;
    }

    // q[b,o,n] = max_k y (BN affine + leaky are monotone -> applied in reduce)
    float* qb = q + (size_t)b * COUT * NPTS + n;
#pragma unroll
    for (int o = 0; o < COUT; o++) {
        float w0 = sW[o * 6 + 0], w1 = sW[o * 6 + 1], w2 = sW[o * 6 + 2];
        float w3 = sW[o * 6 + 3], w4 = sW[o * 6 + 4], w5 = sW[o * 6 + 5];
        float mx = -FLT_MAX;
#pragma unroll
        for (int k = 0; k < K_NN; k++) {
            float y = w0 * f[0][k] + w1 * f[1][k] + w2 * f[2][k] +
                      w3 * f[3][k] + w4 * f[4][k] + w5 * f[5][k];
            mx = fmaxf(mx, y);
        }
        qb[(size_t)o * NPTS] = mx;
    }

    // moment stats: S1[6], S2[21]
    float s1[CIN];
#pragma unroll
    for (int c = 0; c < CIN; c++) {
        float s = 0.f;
#pragma unroll
        for (int k = 0; k < K_NN; k++) s += f[c][k];
        s1[c] = s;
    }
    float s2[21];
#pragma unroll
    for (int i = 0; i < 21; i++) s2[i] = 0.f;
#pragma unroll
    for (int k = 0; k < K_NN; k++) {
        int pp = 0;
#pragma unroll
        for (int c = 0; c < CIN; c++)
#pragma unroll
            for (int c2 = c; c2 < CIN; c2++) {
                s2[pp] += f[c][k] * f[c2][k];
                pp++;
            }
    }
#pragma unroll
    for (int c = 0; c < CIN; c++) s1[c] = wave_sum(s1[c]);
#pragma unroll
    for (int i = 0; i < 21; i++) s2[i] = wave_sum(s2[i]);

    int wv = threadIdx.x >> 6;
    int ln = threadIdx.x & 63;
    if (ln == 0) {
#pragma unroll
        for (int c = 0; c < CIN; c++) sred[wv][c] = s1[c];
#pragma unroll
        for (int i = 0; i < 21; i++) sred[wv][6 + i] = s2[i];
    }
    __syncthreads();
    if (threadIdx.x < 27) {
        float t = sred[0][threadIdx.x] + sred[1][threadIdx.x] +
                  sred[2][threadIdx.x] + sred[3][threadIdx.x];
        atomicAdd(&stats[threadIdx.x], (double)t);
    }
}

// ---- Kernel C: fold moments -> scale/shift (in-block); leaky; reduce max+mean ----
__global__ __launch_bounds__(256) void reduce_kernel(const float* __restrict__ q,
                                                     const double* __restrict__ stats,
                                                     const float* __restrict__ W,
                                                     const float* __restrict__ gamma,
                                                     const float* __restrict__ beta,
                                                     float* __restrict__ out) {
    int o = blockIdx.x;
    int b = blockIdx.y;

    __shared__ float s_sc, s_sh;
    if (threadIdx.x == 0) {
        const double minv = 1.0 / (double)((size_t)BATCH * NPTS * K_NN);
        double w[CIN];
#pragma unroll
        for (int c = 0; c < CIN; c++) w[c] = (double)W[o * CIN + c];
        double mu = 0.0;
#pragma unroll
        for (int c = 0; c < CIN; c++) mu += w[c] * stats[c];
        mu *= minv;
        double ey2 = 0.0;
        int pp = 6;
#pragma unroll
        for (int c = 0; c < CIN; c++)
#pragma unroll
            for (int c2 = c; c2 < CIN; c2++) {
                double v = w[c] * w[c2] * stats[pp];
                ey2 += (c2 == c) ? v : 2.0 * v;
                pp++;
            }
        ey2 *= minv;
        double var = ey2 - mu * mu;
        float scale = gamma[o] * rsqrtf((float)var + BN_EPS);
        float shift = beta[o] - (float)mu * scale;
        s_sc = scale;
        s_sh = shift;
    }
    __syncthreads();
    float scale = s_sc, shift = s_sh;

    const float* qp = q + ((size_t)b * COUT + o) * NPTS;
    float mx = -FLT_MAX, sm = 0.f;
    for (int i = threadIdx.x; i < NPTS; i += 256) {
        float z = scale * qp[i] + shift;
        z = (z >= 0.f) ? z : NEG_SLOPE * z;
        mx = fmaxf(mx, z);
        sm += z;
    }
    mx = wave_max(mx);
    sm = wave_sum(sm);
    __shared__ float smx[4], ssm2[4];
    int wv = threadIdx.x >> 6;
    int ln = threadIdx.x & 63;
    if (ln == 0) { smx[wv] = mx; ssm2[wv] = sm; }
    __syncthreads();
    if (threadIdx.x == 0) {
        float m = fmaxf(fmaxf(smx[0], smx[1]), fmaxf(smx[2], smx[3]));
        float s = ssm2[0] + ssm2[1] + ssm2[2] + ssm2[3];
        out[b * 2 * COUT + o] = m;
        out[b * 2 * COUT + COUT + o] = s * (1.0f / (float)NPTS);
    }
}

extern "C" void kernel_launch(void* const* d_in, const int* in_sizes, int n_in,
                              void* d_out, int out_size, void* d_ws, size_t ws_size,
                              hipStream_t stream) {
    const float* x     = (const float*)d_in[0];
    const float* W     = (const float*)d_in[1];
    const float* gamma = (const float*)d_in[2];
    const float* beta  = (const float*)d_in[3];
    float* out = (float*)d_out;

    char* ws = (char*)d_ws;
    int*    idx   = (int*)(ws + OFF_IDX);
    float4* pts   = (float4*)(ws + OFF_PTS);
    unsigned short* part = (unsigned short*)(ws + OFF_Q); // aliases q (consumed first)
    float*  q     = (float*)(ws + OFF_Q);
    double* stats = (double*)(ws + OFF_ST);

    prep_pts<<<BATCH * NPTS / 256, 256, 0, stream>>>(x, pts, stats);
    knn_part<<<dim3(NPTS / 256, BATCH, NSEG), 256, 0, stream>>>(pts, part);
    merge_kernel<<<dim3(NPTS / 256, BATCH), 256, 0, stream>>>(pts, part, idx);
    feat_kernel<<<dim3(NPTS / 256, BATCH), 256, 0, stream>>>(pts, x, W, idx, q, stats);
    reduce_kernel<<<dim3(COUT, BATCH), 256, 0, stream>>>(q, stats, W, gamma, beta, out);
}

// Round 6
// 180.196 us; speedup vs baseline: 1.3808x; 1.3808x over previous
//
#include <hip/hip_runtime.h>
#include <float.h>

#define K_NN 10
#define BATCH 8
#define CIN 6
#define NPTS 4096
#define COUT 64
#define NSEG 8
#define SEGLEN (NPTS / NSEG)    // 512
#define CHUNK 16
#define NCHUNK (SEGLEN / CHUNK) // 32
#define NWORD (SEGLEN / 32)     // 16
#define NEG_SLOPE 0.2f
#define BN_EPS 1e-5f

// ---- workspace layout (bytes) ---- (identical to verified round-4 layout)
// part[] aliases q[]: part is fully consumed by merge_kernel before feat_kernel writes q.
static constexpr size_t OFF_IDX = 0;                                                   // int[8*10*4096]  (plane layout [b][j][n])
static constexpr size_t OFF_PTS = OFF_IDX + (size_t)BATCH * K_NN * NPTS * sizeof(int); // float4[8*4096]
static constexpr size_t OFF_Q   = OFF_PTS + (size_t)BATCH * NPTS * sizeof(float4);     // alias: q / part
static constexpr size_t SZ_Q    = (size_t)NSEG * BATCH * NPTS * K_NN * sizeof(int);    // 10.49 MB
static constexpr size_t OFF_ST  = OFF_Q + SZ_Q;                                        // double[27]

__device__ __forceinline__ float wave_sum(float v) {
#pragma unroll
    for (int m = 32; m >= 1; m >>= 1) v += __shfl_xor(v, m, 64);
    return v;
}
__device__ __forceinline__ float wave_max(float v) {
#pragma unroll
    for (int m = 32; m >= 1; m >>= 1) v = fmaxf(v, __shfl_xor(v, m, 64));
    return v;
}

// pts stores (2x, 2y, 2z, ||p||^2); query coords pre-halved once per thread.
// d' = 2*inner - ||c||^2 -> 3 FMAs. Monotone shift of true distance, used
// consistently in knn_part/drain/merge. DO NOT reorder (bit-stable).
__device__ __forceinline__ float distp(float qx, float qy, float qz, float4 c) {
    return fmaf(c.x, qx, fmaf(c.y, qy, fmaf(c.z, qz, -c.w)));
}

__device__ __forceinline__ float fmax3(float a, float b, float c) {
    return fmaxf(fmaxf(a, b), c);   // fuses to v_max3_f32 (exact for non-NaN)
}

// 10-deep chunk-max chain level: { hi = max(cj,t); t = min(cj,t); cj = hi; }
#define CHL(cj) { float _hi = fmaxf(cj, t); t = fminf(cj, t); cj = _hi; }

// one conditional swap level of the insertion sort
#define CSWP(va, vb, ia, ib) \
    if (va > vb) { float _tv = va; va = vb; vb = _tv; int _ti = ia; ia = ib; ib = _ti; }

// exact strict-> insertion of (d,m) into descending list v0..v9 / i0..i9
#define INSERT10(dd, mm) \
    if ((dd) > v9) { \
        v9 = (dd); i9 = (mm); \
        CSWP(v9, v8, i9, i8) \
        CSWP(v8, v7, i8, i7) \
        CSWP(v7, v6, i7, i6) \
        CSWP(v6, v5, i6, i5) \
        CSWP(v5, v4, i5, i4) \
        CSWP(v4, v3, i4, i3) \
        CSWP(v3, v2, i3, i2) \
        CSWP(v2, v1, i2, i1) \
        CSWP(v1, v0, i1, i0) \
    }

// ---- Kernel P: pack (2x,2y,2z,||p||^2) per point; block 0 zeroes stats ----
__global__ __launch_bounds__(256) void prep_pts(const float* __restrict__ x,
                                                float4* __restrict__ pts,
                                                double* __restrict__ stats) {
    if (blockIdx.x == 0 && threadIdx.x < 27) stats[threadIdx.x] = 0.0;
    int t = blockIdx.x * 256 + threadIdx.x;   // 0..32767
    int b = t >> 12;
    int n = t & (NPTS - 1);
    const float* xb = x + (size_t)b * CIN * NPTS;
    float x0 = xb[n];
    float x1 = xb[NPTS + n];
    float x2 = xb[2 * NPTS + n];
    pts[t] = make_float4(2.0f * x0, 2.0f * x1, 2.0f * x2, x0 * x0 + x1 * x1 + x2 * x2);
}

// ---- Kernel A1: per-segment exact top-10 (verified round-4 configuration) ----
// One wave per (64 queries, segment). Wave-uniform candidate address -> scalar
// loads; no LDS, no barriers. Measured floor ~79 us across 3 structural
// variants (rounds 1/3/4/5) -- issue-bound; do not restructure.
__global__ __launch_bounds__(256, 4) void knn_part(const float4* __restrict__ pts,
                                                   int* __restrict__ part) {
    int b = blockIdx.y;
    int s = blockIdx.z;
    int n = blockIdx.x * 256 + threadIdx.x;
    const float4* p = pts + (size_t)b * NPTS;   // wave-uniform base -> scalar loads
    float4 q4 = p[n];
    float qx = 0.5f * q4.x, qy = 0.5f * q4.y, qz = 0.5f * q4.z;
    int m0 = s * SEGLEN;

    // ---- phase 1: threshold from chunk maxima ----
    float c0 = -FLT_MAX, c1 = -FLT_MAX, c2 = -FLT_MAX, c3 = -FLT_MAX, c4 = -FLT_MAX;
    float c5 = -FLT_MAX, c6 = -FLT_MAX, c7 = -FLT_MAX, c8 = -FLT_MAX, c9 = -FLT_MAX;

    for (int ch = 0; ch < NCHUNK; ch++) {
        const float4* cp = p + (m0 + ch * CHUNK);
        float d0  = distp(qx, qy, qz, cp[0]);
        float d1  = distp(qx, qy, qz, cp[1]);
        float d2  = distp(qx, qy, qz, cp[2]);
        float d3  = distp(qx, qy, qz, cp[3]);
        float d4  = distp(qx, qy, qz, cp[4]);
        float d5  = distp(qx, qy, qz, cp[5]);
        float d6  = distp(qx, qy, qz, cp[6]);
        float d7  = distp(qx, qy, qz, cp[7]);
        float d8  = distp(qx, qy, qz, cp[8]);
        float d9  = distp(qx, qy, qz, cp[9]);
        float d10 = distp(qx, qy, qz, cp[10]);
        float d11 = distp(qx, qy, qz, cp[11]);
        float d12 = distp(qx, qy, qz, cp[12]);
        float d13 = distp(qx, qy, qz, cp[13]);
        float d14 = distp(qx, qy, qz, cp[14]);
        float d15 = distp(qx, qy, qz, cp[15]);
        float a0 = fmax3(d0, d1, d2);
        float a1 = fmax3(d3, d4, d5);
        float a2 = fmax3(d6, d7, d8);
        float a3 = fmax3(d9, d10, d11);
        float a4 = fmax3(d12, d13, d14);
        float t = fmaxf(fmax3(fmax3(a0, a1, a2), a3, a4), d15);
        CHL(c0) CHL(c1) CHL(c2) CHL(c3) CHL(c4)
        CHL(c5) CHL(c6) CHL(c7) CHL(c8) CHL(c9)
    }
    float thr = c9;   // 10th-largest chunk max (<= exact v10)

    // ---- phase 2 + drain: bitmask survivors, exact strict-> insert ----
    float v0 = -FLT_MAX, v1 = -FLT_MAX, v2 = -FLT_MAX, v3 = -FLT_MAX, v4 = -FLT_MAX;
    float v5 = -FLT_MAX, v6 = -FLT_MAX, v7 = -FLT_MAX, v8 = -FLT_MAX, v9 = -FLT_MAX;
    int i0 = 0, i1 = 0, i2 = 0, i3 = 0, i4 = 0;
    int i5 = 0, i6 = 0, i7 = 0, i8 = 0, i9 = 0;

    for (int w = 0; w < NWORD; w++) {
        const float4* cp = p + (m0 + w * 32);
        unsigned int mask = 0u;
#pragma unroll
        for (int u = 0; u < 32; u++) {
            float d = distp(qx, qy, qz, cp[u]);
            mask = (mask << 1) | (d >= thr ? 1u : 0u);   // point u -> bit (31-u)
        }
        int base = m0 + w * 32;
        while (mask) {
            int j = __builtin_clz(mask);        // MSB-first == ascending m
            mask ^= (0x80000000u >> j);
            int m = base + j;
            float4 cc = p[m];                   // divergent, L1-hot (segment = 8 KB)
            float d = distp(qx, qy, qz, cc);
            INSERT10(d, m)
        }
    }

    int* o = part + (((size_t)s * BATCH + b) * K_NN) * NPTS + n;
    o[(size_t)0 * NPTS] = i0;
    o[(size_t)1 * NPTS] = i1;
    o[(size_t)2 * NPTS] = i2;
    o[(size_t)3 * NPTS] = i3;
    o[(size_t)4 * NPTS] = i4;
    o[(size_t)5 * NPTS] = i5;
    o[(size_t)6 * NPTS] = i6;
    o[(size_t)7 * NPTS] = i7;
    o[(size_t)8 * NPTS] = i8;
    o[(size_t)9 * NPTS] = i9;
}

// ---- Kernel A2: merge 8 segment lists -> global top-10, 4-wave cooperative ----
// ROUND-6: previous merge ran 512 waves on 1024 SIMDs (0.5/SIMD, latency-bound
// divergent gathers). Now: block = 4 waves x same 64 queries; wave w scans
// segments {2w, 2w+1} (20 cands), publishes top-10 via LDS; wave 0 merges
// 4x10 in (w asc, j asc) == ascending candidate order -> identical tie
// semantics (round-3-proven pattern). 2048 waves, serial chain 80 -> 20.
__global__ __launch_bounds__(256, 8) void merge_kernel(const float4* __restrict__ pts,
                                                       const int* __restrict__ part,
                                                       int* __restrict__ idxo) {
    __shared__ float dml[4][K_NN][64];
    __shared__ unsigned short iml[4][K_NN][64];

    int b  = blockIdx.y;
    int ln = threadIdx.x & 63;
    int wv = threadIdx.x >> 6;
    int wvu = __builtin_amdgcn_readfirstlane(wv);   // uniform (round-2 lesson)
    int n  = blockIdx.x * 64 + ln;
    const float4* p = pts + (size_t)b * NPTS;
    float4 q4 = p[n];
    float qx = 0.5f * q4.x, qy = 0.5f * q4.y, qz = 0.5f * q4.z;

    float v0 = -FLT_MAX, v1 = -FLT_MAX, v2 = -FLT_MAX, v3 = -FLT_MAX, v4 = -FLT_MAX;
    float v5 = -FLT_MAX, v6 = -FLT_MAX, v7 = -FLT_MAX, v8 = -FLT_MAX, v9 = -FLT_MAX;
    int i0 = 0, i1 = 0, i2 = 0, i3 = 0, i4 = 0;
    int i5 = 0, i6 = 0, i7 = 0, i8 = 0, i9 = 0;

#pragma unroll
    for (int t = 0; t < 2; t++) {
        int s = 2 * wvu + t;                     // uniform segment id
        const int* pp = part + (((size_t)s * BATCH + b) * K_NN) * NPTS + n;
#pragma unroll
        for (int j = 0; j < K_NN; j++) {
            int m = pp[(size_t)j * NPTS];
            float4 cc = p[m];                    // divergent but L1/L2-resident
            float d = distp(qx, qy, qz, cc);
            INSERT10(d, m)
        }
    }

    dml[wv][0][ln] = v0; iml[wv][0][ln] = (unsigned short)i0;
    dml[wv][1][ln] = v1; iml[wv][1][ln] = (unsigned short)i1;
    dml[wv][2][ln] = v2; iml[wv][2][ln] = (unsigned short)i2;
    dml[wv][3][ln] = v3; iml[wv][3][ln] = (unsigned short)i3;
    dml[wv][4][ln] = v4; iml[wv][4][ln] = (unsigned short)i4;
    dml[wv][5][ln] = v5; iml[wv][5][ln] = (unsigned short)i5;
    dml[wv][6][ln] = v6; iml[wv][6][ln] = (unsigned short)i6;
    dml[wv][7][ln] = v7; iml[wv][7][ln] = (unsigned short)i7;
    dml[wv][8][ln] = v8; iml[wv][8][ln] = (unsigned short)i8;
    dml[wv][9][ln] = v9; iml[wv][9][ln] = (unsigned short)i9;
    __syncthreads();

    if (wvu == 0) {
        float v0 = -FLT_MAX, v1 = -FLT_MAX, v2 = -FLT_MAX, v3 = -FLT_MAX, v4 = -FLT_MAX;
        float v5 = -FLT_MAX, v6 = -FLT_MAX, v7 = -FLT_MAX, v8 = -FLT_MAX, v9 = -FLT_MAX;
        int i0 = 0, i1 = 0, i2 = 0, i3 = 0, i4 = 0;
        int i5 = 0, i6 = 0, i7 = 0, i8 = 0, i9 = 0;
#pragma unroll
        for (int w = 0; w < 4; w++) {
#pragma unroll
            for (int j = 0; j < K_NN; j++) {
                float d = dml[w][j][ln];
                int m = iml[w][j][ln];
                INSERT10(d, m)
            }
        }
        int* o = idxo + (size_t)b * K_NN * NPTS + n;
        o[(size_t)0 * NPTS] = i0;
        o[(size_t)1 * NPTS] = i1;
        o[(size_t)2 * NPTS] = i2;
        o[(size_t)3 * NPTS] = i3;
        o[(size_t)4 * NPTS] = i4;
        o[(size_t)5 * NPTS] = i5;
        o[(size_t)6 * NPTS] = i6;
        o[(size_t)7 * NPTS] = i7;
        o[(size_t)8 * NPTS] = i8;
        o[(size_t)9 * NPTS] = i9;
    }
}

// ---- Kernel B: gather + center + q[b,o,n] = max_k (W feat) + moment stats ----
// ROUND-6: grid.z = 4 output-groups (16 outputs each). Gather/center redone
// per group (cheap, L2-hot) but FMA work per thread drops 3840 -> 960 and
// wave count rises 512 -> 2048 (was 0.5/SIMD). Stats only in z==0 blocks:
// same threads, same wave composition, same op order -> bit-identical.
__global__ __launch_bounds__(256) void feat_kernel(const float4* __restrict__ pts,
                                                   const float* __restrict__ x,
                                                   const float* __restrict__ W,
                                                   const int* __restrict__ idx,
                                                   float* __restrict__ q,
                                                   double* __restrict__ stats) {
    __shared__ float sW[COUT * CIN];
    __shared__ float sred[4][27];
    for (int i = threadIdx.x; i < COUT * CIN; i += 256) sW[i] = W[i];
    __syncthreads();

    int b = blockIdx.y;
    int og = blockIdx.z;           // output group: o in [16*og, 16*og+16)
    int n = blockIdx.x * 256 + threadIdx.x;
    const float* xb = x + (size_t)b * CIN * NPTS;
    const float4* p = pts + (size_t)b * NPTS;

    int nb[K_NN];
#pragma unroll
    for (int k = 0; k < K_NN; k++) nb[k] = idx[((size_t)b * K_NN + k) * NPTS + n];

    float f[CIN][K_NN];
#pragma unroll
    for (int k = 0; k < K_NN; k++) {
        float4 c = p[nb[k]];                    // xyz in one 16B gather (doubled)
        f[0][k] = 0.5f * c.x; f[1][k] = 0.5f * c.y; f[2][k] = 0.5f * c.z;
    }
#pragma unroll
    for (int c = 3; c < CIN; c++)
#pragma unroll
        for (int k = 0; k < K_NN; k++)
            f[c][k] = xb[c * NPTS + nb[k]];

    // center xyz over k, scale by 10
#pragma unroll
    for (int c = 0; c < 3; c++) {
        float s = 0.f;
#pragma unroll
        for (int k = 0; k < K_NN; k++) s += f[c][k];
        float m = s / 10.0f;
#pragma unroll
        for (int k = 0; k < K_NN; k++) f[c][k] = (f[c][k] - m) * 10.0f;
    }

    // q[b,o,n] = max_k y for this block's 16 outputs (same per-o op order)
    float* qb = q + (size_t)b * COUT * NPTS + n;
    int o0 = og * 16;
#pragma unroll
    for (int oo = 0; oo < 16; oo++) {
        int o = o0 + oo;
        float w0 = sW[o * 6 + 0], w1 = sW[o * 6 + 1], w2 = sW[o * 6 + 2];
        float w3 = sW[o * 6 + 3], w4 = sW[o * 6 + 4], w5 = sW[o * 6 + 5];
        float mx = -FLT_MAX;
#pragma unroll
        for (int k = 0; k < K_NN; k++) {
            float y = w0 * f[0][k] + w1 * f[1][k] + w2 * f[2][k] +
                      w3 * f[3][k] + w4 * f[4][k] + w5 * f[5][k];
            mx = fmaxf(mx, y);
        }
        qb[(size_t)o * NPTS] = mx;
    }

    if (og != 0) return;   // stats once (block-uniform branch; sync below is safe)

    // moment stats: S1[6], S2[21]
    float s1[CIN];
#pragma unroll
    for (int c = 0; c < CIN; c++) {
        float s = 0.f;
#pragma unroll
        for (int k = 0; k < K_NN; k++) s += f[c][k];
        s1[c] = s;
    }
    float s2[21];
#pragma unroll
    for (int i = 0; i < 21; i++) s2[i] = 0.f;
#pragma unroll
    for (int k = 0; k < K_NN; k++) {
        int pp = 0;
#pragma unroll
        for (int c = 0; c < CIN; c++)
#pragma unroll
            for (int c2 = c; c2 < CIN; c2++) {
                s2[pp] += f[c][k] * f[c2][k];
                pp++;
            }
    }
#pragma unroll
    for (int c = 0; c < CIN; c++) s1[c] = wave_sum(s1[c]);
#pragma unroll
    for (int i = 0; i < 21; i++) s2[i] = wave_sum(s2[i]);

    int wv = threadIdx.x >> 6;
    int ln = threadIdx.x & 63;
    if (ln == 0) {
#pragma unroll
        for (int c = 0; c < CIN; c++) sred[wv][c] = s1[c];
#pragma unroll
        for (int i = 0; i < 21; i++) sred[wv][6 + i] = s2[i];
    }
    __syncthreads();
    if (threadIdx.x < 27) {
        float t = sred[0][threadIdx.x] + sred[1][threadIdx.x] +
                  sred[2][threadIdx.x] + sred[3][threadIdx.x];
        atomicAdd(&stats[threadIdx.x], (double)t);
    }
}

// ---- Kernel C: fold moments -> scale/shift (in-block); leaky; reduce max+mean ----
__global__ __launch_bounds__(256) void reduce_kernel(const float* __restrict__ q,
                                                     const double* __restrict__ stats,
                                                     const float* __restrict__ W,
                                                     const float* __restrict__ gamma,
                                                     const float* __restrict__ beta,
                                                     float* __restrict__ out) {
    int o = blockIdx.x;
    int b = blockIdx.y;

    __shared__ float s_sc, s_sh;
    if (threadIdx.x == 0) {
        const double minv = 1.0 / (double)((size_t)BATCH * NPTS * K_NN);
        double w[CIN];
#pragma unroll
        for (int c = 0; c < CIN; c++) w[c] = (double)W[o * CIN + c];
        double mu = 0.0;
#pragma unroll
        for (int c = 0; c < CIN; c++) mu += w[c] * stats[c];
        mu *= minv;
        double ey2 = 0.0;
        int pp = 6;
#pragma unroll
        for (int c = 0; c < CIN; c++)
#pragma unroll
            for (int c2 = c; c2 < CIN; c2++) {
                double v = w[c] * w[c2] * stats[pp];
                ey2 += (c2 == c) ? v : 2.0 * v;
                pp++;
            }
        ey2 *= minv;
        double var = ey2 - mu * mu;
        float scale = gamma[o] * rsqrtf((float)var + BN_EPS);
        float shift = beta[o] - (float)mu * scale;
        s_sc = scale;
        s_sh = shift;
    }
    __syncthreads();
    float scale = s_sc, shift = s_sh;

    const float* qp = q + ((size_t)b * COUT + o) * NPTS;
    float mx = -FLT_MAX, sm = 0.f;
    for (int i = threadIdx.x; i < NPTS; i += 256) {
        float z = scale * qp[i] + shift;
        z = (z >= 0.f) ? z : NEG_SLOPE * z;
        mx = fmaxf(mx, z);
        sm += z;
    }
    mx = wave_max(mx);
    sm = wave_sum(sm);
    __shared__ float smx[4], ssm2[4];
    int wv = threadIdx.x >> 6;
    int ln = threadIdx.x & 63;
    if (ln == 0) { smx[wv] = mx; ssm2[wv] = sm; }
    __syncthreads();
    if (threadIdx.x == 0) {
        float m = fmaxf(fmaxf(smx[0], smx[1]), fmaxf(smx[2], smx[3]));
        float s = ssm2[0] + ssm2[1] + ssm2[2] + ssm2[3];
        out[b * 2 * COUT + o] = m;
        out[b * 2 * COUT + COUT + o] = s * (1.0f / (float)NPTS);
    }
}

extern "C" void kernel_launch(void* const* d_in, const int* in_sizes, int n_in,
                              void* d_out, int out_size, void* d_ws, size_t ws_size,
                              hipStream_t stream) {
    const float* x     = (const float*)d_in[0];
    const float* W     = (const float*)d_in[1];
    const float* gamma = (const float*)d_in[2];
    const float* beta  = (const float*)d_in[3];
    float* out = (float*)d_out;

    char* ws = (char*)d_ws;
    int*    idx   = (int*)(ws + OFF_IDX);
    float4* pts   = (float4*)(ws + OFF_PTS);
    int*    part  = (int*)(ws + OFF_Q);     // aliases q region (consumed before q written)
    float*  q     = (float*)(ws + OFF_Q);
    double* stats = (double*)(ws + OFF_ST);

    prep_pts<<<BATCH * NPTS / 256, 256, 0, stream>>>(x, pts, stats);
    knn_part<<<dim3(NPTS / 256, BATCH, NSEG), 256, 0, stream>>>(pts, part);
    merge_kernel<<<dim3(NPTS / 64, BATCH), 256, 0, stream>>>(pts, part, idx);
    feat_kernel<<<dim3(NPTS / 256, BATCH, 4), 256, 0, stream>>>(pts, x, W, idx, q, stats);
    reduce_kernel<<<dim3(COUT, BATCH), 256, 0, stream>>>(q, stats, W, gamma, beta, out);
}